// Round 8
// baseline (142.453 us; speedup 1.0000x reference)
//
#include <hip/hip_runtime.h>
#include <cstdint>
#include <cstddef>

// ---------------- problem constants ----------------
#define NB    32          // batch
#define CI    128         // in channels
#define CO    256         // out channels
#define HW_   56          // spatial
#define HP    58          // padded spatial
#define KTOT  1152        // 128*9 reduction
#define NKT   36          // K-tiles of 32
#define MTOT  (NB * HW_ * HW_)   // 100352 output pixels

static constexpr size_t XP_ELEMS = (size_t)NB * HP * HP * CI;   // 13,776,896
static constexpr size_t WT_ELEMS = (size_t)CO * KTOT;           // 294,912
static constexpr size_t XP_BYTES = XP_ELEMS * 2;
static constexpr size_t WT_BYTES = WT_ELEMS * 2;

typedef __attribute__((ext_vector_type(8))) short bf16x8;
typedef __attribute__((ext_vector_type(8))) short short8v;
typedef __attribute__((ext_vector_type(4))) float f32x4;

__device__ __forceinline__ short f32_to_bf16(float f) {
  uint32_t u = __float_as_uint(f);
  uint32_t r = (u + 0x7FFFu + ((u >> 16) & 1u)) >> 16;
  return (short)r;
}

typedef __attribute__((address_space(3))) void       lds_void;
typedef const __attribute__((address_space(1))) void gbl_void;

__device__ __forceinline__ void gload16(const void* g, void* l) {
  // dest = wave-uniform LDS base; HW writes lane's 16B at base + lane*16
  __builtin_amdgcn_global_load_lds((gbl_void*)g, (lds_void*)l, 16, 0, 0);
}

// ---- pre-pass: x NCHW f32 -> padded NHWC bf16; wt -> FRAGMENT-MAJOR bf16 ----
// wbF layout: frag idx = (g2*36 + v)*64 + lane, 8 bf16 each:
//   oc = g2*16 + (lane&15); k-local = (lane>>4)*8 + j of K-tile v
//   (tile v: tap = v>>2 -> kh,kw; channels c = (v&3)*32 + klocal)
// => LOAD_B in GEMM is one fully-coalesced 16B/lane read per 16-oc group.
// NOTE (R7 bug fix): each thread writes a short8 -> only WT_ELEMS/8 = 36864
// threads = 144 blocks. R7 used 1152 blocks -> 8x overrun -> memory fault.
__global__ void pad_convert(const float* __restrict__ x, short* __restrict__ xp,
                            const float* __restrict__ wt, short* __restrict__ wbF) {
  __shared__ float lds[CI][57];
  const int blk = blockIdx.x;    // NB*HP = 1856
  const int hp  = blk % HP;
  const int nb  = blk / HP;
  const int tid = threadIdx.x;   // 256

  // weight conversion folded into the first 144 blocks (144*256*8 == WT_ELEMS)
  if (blk < 144) {
    const int idx = blk * 256 + tid;        // 0..36863 (frag index)
    const int lam = idx & 63;
    const int v   = (idx >> 6) % NKT;
    const int g2  = idx / (64 * NKT);       // 0..15
    const int oc  = g2 * 16 + (lam & 15);
    const int tap = v >> 2;
    const int kh  = tap / 3, kw = tap - kh * 3;
    const int c0  = (v & 3) * 32 + (lam >> 4) * 8;
    short8v s;
#pragma unroll
    for (int j = 0; j < 8; ++j)
      s[j] = f32_to_bf16(wt[(((size_t)oc * CI + c0 + j) * 3 + kh) * 3 + kw]);
    *(short8v*)(wbF + (size_t)idx * 8) = s;
  }

  const bool interior = (hp >= 1 && hp <= HW_);
  if (interior) {
    const float* src = x + (size_t)nb * CI * HW_ * HW_ + (size_t)(hp - 1) * HW_;
    for (int t = tid; t < CI * HW_; t += 256) {
      int c = t / HW_, w = t - (t / HW_) * HW_;
      lds[c][w] = src[(size_t)c * HW_ * HW_ + w];
    }
  }
  __syncthreads();
  short* dst = xp + (size_t)(nb * HP + hp) * HP * CI;
  for (int t = tid; t < HP * CI / 4; t += 256) {
    const int wp = t >> 5;          // 32 channel-quads per wp
    const int c4 = (t & 31) * 4;
    short4 s;
    if (interior && wp >= 1 && wp <= HW_) {
      s.x = f32_to_bf16(lds[c4 + 0][wp - 1]);
      s.y = f32_to_bf16(lds[c4 + 1][wp - 1]);
      s.z = f32_to_bf16(lds[c4 + 2][wp - 1]);
      s.w = f32_to_bf16(lds[c4 + 3][wp - 1]);
    } else {
      s.x = s.y = s.z = s.w = 0;
    }
    *(short4*)(dst + t * 4) = s;
  }
}

// scalar byte offset into an xp pixel row for K-tile u (tap + channel-quarter)
__device__ __forceinline__ int stage_aoff(int u) {
  const int tap = u >> 2;            // 0..8
  const int cq  = u & 3;             // channel quarter (32 ch)
  const int kh  = tap / 3, kw = tap - kh * 3;
  return ((kh * HP + kw) * CI + cq * 32) * 2;
}

// ---------------- main: implicit GEMM, 256x128 tile, BK=32, 4 waves ----------------
// R8 (theory: LDS co-limiting at R4's 144KB/CU/tile; cut to 96KB):
//  * A through LDS exactly as R4 (proven zero-conflict swizzle, 16x16x32 MFMA).
//  * B NEVER touches LDS: fragment-major wbF -> 4 coalesced dwordx4 per wave
//    per tile into reg double-buffer (bfP/bfQ), prefetched 1 tile ahead.
//  * Per-tile issue order: LOAD_B(v+1) then STAGE_A(v+2) => uniform vmcnt(4)
//    at each boundary leaves only A(v+2) outstanding, confirming A(v+1) and
//    B(v+1); compiler auto-waits B-reg deps. No vmcnt(0) in the loop.
// LDS: 3 A-buffers x 16KB = 48KB -> 2 blocks/CU.
__global__ __launch_bounds__(256, 2) void conv_gemm(
    const short* __restrict__ xp, const short* __restrict__ wbF,
    const float* __restrict__ bias, float* __restrict__ out) {
  __shared__ __align__(16) char lds_[3 * 16384];

  const int tid = threadIdx.x;     // 256
  const int l   = tid & 63;
  const int wv  = tid >> 6;        // 0..3
  const int wm  = wv >> 1;         // 0..1  (m half: 128 rows)
  const int wn  = wv & 1;          // 0..1  (oc half: 64 cols)

  // grid 784 = 8 XCDs x 98; chunked bijective swizzle, nt inner (A reuse in L2)
  const int bid = blockIdx.x;
  const int lin = (bid & 7) * 98 + (bid >> 3);
  const int mt  = lin >> 1;
  const int nt  = lin & 1;

  // ---- A staging source pointers (pre-swizzled per rule #21) ----
  // gload g covers rows 64g + 16wv + (l>>2); lane piece (l&3); src piece ^((l>>3)&3)
  const int pcs  = (((l & 3) ^ ((l >> 3) & 3)) << 4);
  const int srow = 16 * wv + (l >> 2);                 // 0..63 per gload group
  const char *aSrc0, *aSrc1, *aSrc2, *aSrc3;
  {
#pragma unroll
    for (int g = 0; g < 4; ++g) {
      int m  = mt * 256 + 64 * g + srow;
      int nb = m / 3136, hw = m - nb * 3136;
      int h = hw / HW_, w = hw - (hw / HW_) * HW_;
      const char* p = (const char*)xp + ((size_t)((nb * HP + h) * HP + w) * CI) * 2 + pcs;
      if (g == 0) aSrc0 = p; else if (g == 1) aSrc1 = p;
      else if (g == 2) aSrc2 = p; else aSrc3 = p;
    }
  }

  // ---- B fragment-major lane addresses: group g2 = nt*8 + wn*4 + h ----
  // bAddr_h + v*1024 is lane l's 16B of (g2, tile v): fully coalesced per wave.
  const char* bAddr0 = (const char*)wbF + ((size_t)((nt * 8 + wn * 4 + 0) * NKT) * 64 + l) * 16;
  const char* bAddr1 = (const char*)wbF + ((size_t)((nt * 8 + wn * 4 + 1) * NKT) * 64 + l) * 16;
  const char* bAddr2 = (const char*)wbF + ((size_t)((nt * 8 + wn * 4 + 2) * NKT) * 64 + l) * 16;
  const char* bAddr3 = (const char*)wbF + ((size_t)((nt * 8 + wn * 4 + 3) * NKT) * 64 + l) * 16;

  // ---- A frag ds_read offsets (swizzled; verified 0 conflicts R3/R4) ----
  const int lm   = l & 15;
  const int koff = (((l >> 4) ^ ((l >> 1) & 3)) << 4);
  const int raOff = (wm * 128 + lm) * 64 + koff;   // + g*1024, g=0..7

  char* B0 = lds_;
  char* B1 = lds_ + 16384;
  char* B2 = lds_ + 32768;

#define STAGE_A(U, BUF)                                                      \
  {                                                                          \
    const int ao_ = stage_aoff(U);                                           \
    gload16(aSrc0 + ao_, (BUF) +         wv * 1024);                         \
    gload16(aSrc1 + ao_, (BUF) +  4096 + wv * 1024);                         \
    gload16(aSrc2 + ao_, (BUF) +  8192 + wv * 1024);                         \
    gload16(aSrc3 + ao_, (BUF) + 12288 + wv * 1024);                         \
  }
#define LOAD_B(U, BF)                                                        \
  {                                                                          \
    const size_t bo_ = (size_t)(U) * 1024;                                   \
    BF[0] = *(const bf16x8*)(bAddr0 + bo_);                                  \
    BF[1] = *(const bf16x8*)(bAddr1 + bo_);                                  \
    BF[2] = *(const bf16x8*)(bAddr2 + bo_);                                  \
    BF[3] = *(const bf16x8*)(bAddr3 + bo_);                                  \
  }

  f32x4 acc[8][4];
#pragma unroll
  for (int g = 0; g < 8; ++g)
#pragma unroll
    for (int h = 0; h < 4; ++h) acc[g][h] = {0.f, 0.f, 0.f, 0.f};

  bf16x8 bfP[4], bfQ[4];

  // ---- prologue: stage A tiles 0,1; load B tile 0; confirm A0 ----
  STAGE_A(0, B0)
  STAGE_A(1, B1)
  LOAD_B(0, bfP)
  asm volatile("s_waitcnt vmcnt(8)" ::: "memory");   // A(0) landed
  __builtin_amdgcn_s_barrier();
  __builtin_amdgcn_sched_barrier(0);

#define TILE_BODY(V, CUR, STG, BFC, BFN)                                     \
  {                                                                          \
    const int v_ = (V);                                                      \
    if (v_ + 1 < NKT) LOAD_B(v_ + 1, BFN)                                    \
    if (v_ + 2 < NKT) STAGE_A(v_ + 2, STG)                                   \
    bf16x8 af[8];                                                            \
    _Pragma("unroll") for (int g = 0; g < 8; ++g)                            \
        af[g] = *(const bf16x8*)((CUR) + raOff + g * 1024);                  \
    __builtin_amdgcn_s_setprio(1);                                           \
    _Pragma("unroll") for (int g = 0; g < 8; ++g)                            \
      _Pragma("unroll") for (int h = 0; h < 4; ++h)                          \
        acc[g][h] = __builtin_amdgcn_mfma_f32_16x16x32_bf16(                 \
            BFC[h], af[g], acc[g][h], 0, 0, 0);                              \
    __builtin_amdgcn_s_setprio(0);                                           \
    if (v_ < NKT - 1) {                                                      \
      asm volatile("s_waitcnt vmcnt(4)" ::: "memory");                       \
      __builtin_amdgcn_s_barrier();                                          \
      __builtin_amdgcn_sched_barrier(0);                                     \
    }                                                                        \
  }

  // 3-buffer x B-parity => 6-cycle; NKT = 36
  for (int v6 = 0; v6 < NKT; v6 += 6) {
    TILE_BODY(v6 + 0, B0, B2, bfP, bfQ)
    TILE_BODY(v6 + 1, B1, B0, bfQ, bfP)
    TILE_BODY(v6 + 2, B2, B1, bfP, bfQ)
    TILE_BODY(v6 + 3, B0, B2, bfQ, bfP)
    TILE_BODY(v6 + 4, B1, B0, bfP, bfQ)
    TILE_BODY(v6 + 5, B2, B1, bfQ, bfP)
  }
#undef TILE_BODY
#undef STAGE_A
#undef LOAD_B

  // ---- epilogue: D rows = oc, cols = m (swapped operands) -> coalesced stores ----
  const int mBase = mt * 256 + wm * 128 + lm;
  const int ocB   = nt * 128 + wn * 64 + (l >> 4) * 4;
  float bv[4][4];
#pragma unroll
  for (int h = 0; h < 4; ++h)
#pragma unroll
    for (int j = 0; j < 4; ++j) bv[h][j] = bias[ocB + h * 16 + j];
#pragma unroll
  for (int g = 0; g < 8; ++g) {
    const int m  = mBase + g * 16;
    const int nb = m / 3136;
    const int hw = m - nb * 3136;
    float* op = out + (size_t)nb * CO * 3136 + hw;
#pragma unroll
    for (int h = 0; h < 4; ++h) {
      const int oc = ocB + h * 16;
#pragma unroll
      for (int j = 0; j < 4; ++j)
        op[(size_t)(oc + j) * 3136] = acc[g][h][j] + bv[h][j];
    }
  }
}

// ---------------- fallback (ws too small): naive direct conv ----------------
__global__ void conv_naive(const float* __restrict__ x, const float* __restrict__ wt,
                           const float* __restrict__ bias, float* __restrict__ out) {
  const int idx = blockIdx.x * 256 + threadIdx.x;
  if (idx >= NB * CO * 3136) return;
  const int w  = idx % HW_;
  const int h  = (idx / HW_) % HW_;
  const int oc = (idx / 3136) % CO;
  const int nb = idx / (3136 * CO);
  float s = bias[oc];
  for (int c = 0; c < CI; ++c)
    for (int kh = 0; kh < 3; ++kh) {
      const int ih = h + kh - 1;
      if (ih < 0 || ih >= HW_) continue;
      for (int kw = 0; kw < 3; ++kw) {
        const int iw = w + kw - 1;
        if (iw < 0 || iw >= HW_) continue;
        s += x[((size_t)(nb * CI + c) * HW_ + ih) * HW_ + iw] *
             wt[(((size_t)oc * CI + c) * 3 + kh) * 3 + kw];
      }
    }
  out[idx] = s;
}

extern "C" void kernel_launch(void* const* d_in, const int* in_sizes, int n_in,
                              void* d_out, int out_size, void* d_ws, size_t ws_size,
                              hipStream_t stream) {
  const float* x    = (const float*)d_in[0];
  const float* wt   = (const float*)d_in[1];
  const float* bias = (const float*)d_in[2];
  float* out        = (float*)d_out;

  if (ws_size < XP_BYTES + WT_BYTES) {
    conv_naive<<<(NB * CO * 3136 + 255) / 256, 256, 0, stream>>>(x, wt, bias, out);
    return;
  }

  short* xp  = (short*)d_ws;
  short* wbF = (short*)((char*)d_ws + XP_BYTES);

  pad_convert<<<NB * HP, 256, 0, stream>>>(x, xp, wt, wbF);
  conv_gemm<<<(MTOT / 256) * 2, 256, 0, stream>>>(xp, wbF, bias, out);
}

// Round 11
// 95.706 us; speedup vs baseline: 1.4884x; 1.4884x over previous
//
#include <hip/hip_runtime.h>
#include <cstdint>
#include <cstddef>

// ---------------- problem constants ----------------
#define NB    32          // batch
#define CI    128         // in channels
#define CO    256         // out channels
#define HW_   56          // spatial
#define HP    58          // padded spatial
#define KTOT  1152        // 128*9 reduction
#define NKT   36          // K-tiles of 32
#define MTOT  (NB * HW_ * HW_)   // 100352 output pixels

static constexpr size_t XP_ELEMS = (size_t)NB * HP * HP * CI;   // 13,776,896
static constexpr size_t WT_ELEMS = (size_t)CO * KTOT;           // 294,912
static constexpr size_t XP_BYTES = XP_ELEMS * 2;
static constexpr size_t WT_BYTES = WT_ELEMS * 2;

typedef __attribute__((ext_vector_type(8))) short bf16x8;
typedef __attribute__((ext_vector_type(4))) float f32x4;

__device__ __forceinline__ short f32_to_bf16(float f) {
  uint32_t u = __float_as_uint(f);
  uint32_t r = (u + 0x7FFFu + ((u >> 16) & 1u)) >> 16;
  return (short)r;
}

typedef __attribute__((address_space(3))) void       lds_void;
typedef const __attribute__((address_space(1))) void gbl_void;

__device__ __forceinline__ void gload16(const void* g, void* l) {
  // dest = wave-uniform LDS base; HW writes lane's 16B at base + lane*16
  __builtin_amdgcn_global_load_lds((gbl_void*)g, (lds_void*)l, 16, 0, 0);
}

// ---- pre-pass: x NCHW f32 -> padded NHWC bf16; wt OIHW -> [o][kh][kw][c] bf16 ----
// (verified-correct R4 version)
__global__ void pad_convert(const float* __restrict__ x, short* __restrict__ xp,
                            const float* __restrict__ wt, short* __restrict__ wbT) {
  __shared__ float lds[CI][57];
  const int blk = blockIdx.x;    // NB*HP = 1856
  const int hp  = blk % HP;
  const int nb  = blk / HP;
  const int tid = threadIdx.x;   // 256

  if (blk < 1152) {              // 1152*256 == WT_ELEMS (scalar per thread)
    int idx = blk * 256 + tid;
    int c  = idx & 127;
    int t  = idx >> 7;          // o*9 + kh*3 + kw
    int kw = t % 3;  int t2 = t / 3;
    int kh = t2 % 3; int o  = t2 / 3;
    wbT[idx] = f32_to_bf16(wt[(((size_t)o * CI + c) * 3 + kh) * 3 + kw]);
  }

  const bool interior = (hp >= 1 && hp <= HW_);
  if (interior) {
    const float* src = x + (size_t)nb * CI * HW_ * HW_ + (size_t)(hp - 1) * HW_;
    for (int t = tid; t < CI * HW_; t += 256) {
      int c = t / HW_, w = t - (t / HW_) * HW_;
      lds[c][w] = src[(size_t)c * HW_ * HW_ + w];
    }
  }
  __syncthreads();
  short* dst = xp + (size_t)(nb * HP + hp) * HP * CI;
  for (int t = tid; t < HP * CI / 4; t += 256) {
    const int wp = t >> 5;
    const int c4 = (t & 31) * 4;
    short4 s;
    if (interior && wp >= 1 && wp <= HW_) {
      s.x = f32_to_bf16(lds[c4 + 0][wp - 1]);
      s.y = f32_to_bf16(lds[c4 + 1][wp - 1]);
      s.z = f32_to_bf16(lds[c4 + 2][wp - 1]);
      s.w = f32_to_bf16(lds[c4 + 3][wp - 1]);
    } else {
      s.x = s.y = s.z = s.w = 0;
    }
    *(short4*)(dst + t * 4) = s;
  }
}

// scalar byte offset into an xp pixel row for K-tile u (tap + channel-quarter)
__device__ __forceinline__ int stage_aoff(int u) {
  const int tap = u >> 2;            // 0..8
  const int cq  = u & 3;             // channel quarter (32 ch)
  const int kh  = tap / 3, kw = tap - kh * 3;
  return ((kh * HP + kw) * CI + cq * 32) * 2;
}

// ---------------- main: implicit GEMM, 256x256, BK=32, 8 waves ----------------
// R11: R4's PROVEN ledger mechanics (1 counted-wait + 1 barrier per K-tile,
// coarse body, 3 buffers, stage-ahead 2) at the 256x256/8-wave geometry whose
// LDS-byte model caps at 68% (128KB/tile vs 310 MFMA-cyc/SIMD) instead of
// R4's 30% (LDS-saturated at 2 blocks). No mid-tile barriers: waves drift so
// one wave's ds_reads overlap the other SIMD-resident wave's MFMA (m114).
// Hazards: body v stages tile v+2 into buf (v+2)%3 = tile v-1's buffer, whose
// reads all completed before the end-of-(v-1) barrier. Reads of tile v are
// confirmed by end-of-(v-1)'s vmcnt(4) (leaves only tile v+1's 4 loads) +
// barrier. 4 gloads/thread/tile; vmcnt(0) only at v=NKT-2 (outstanding = only
// tile 35's 4 loads). Prologue: stage t0,t1; vmcnt(4); barrier.
// All index math verbatim from R3 (passed, 0 bank conflicts).
__global__ __launch_bounds__(512, 1) void conv_gemm(
    const short* __restrict__ xp, const short* __restrict__ wbT,
    const float* __restrict__ bias, float* __restrict__ out) {
  __shared__ __align__(16) char lds_[3 * 32768];

  const int tid = threadIdx.x;     // 512
  const int l   = tid & 63;
  const int wv  = tid >> 6;        // 0..7
  const int wm  = wv >> 2;         // 0..1  (m half: 128 rows)
  const int wn  = wv & 3;          // 0..3  (oc quarter: 64 cols)
  const int lm  = l & 15;

  // grid 392 = 8 XCDs x 49; bijective chunked swizzle
  const int bid = blockIdx.x;
  const int mt  = (bid & 7) * 49 + (bid >> 3);

  // ---- staging source pointers (pre-swizzled per rule #21; R3 verbatim) ----
  // each gload: thread t writes LDS piece t (row = t>>2, piece = t&3);
  // source holds piece (t&3) ^ ((t>>3)&3)
  const int pcs  = (((tid & 3) ^ ((tid >> 3) & 3)) << 4);
  const int srow = tid >> 2;                  // 0..127
  const char *aSrc0, *aSrc1;
  {
#pragma unroll
    for (int q = 0; q < 2; ++q) {
      int m  = mt * 256 + 128 * q + srow;
      int nb = m / 3136, hw = m - nb * 3136;
      int h = hw / HW_, w = hw - (hw / HW_) * HW_;
      const char* p = (const char*)xp + ((size_t)((nb * HP + h) * HP + w) * CI) * 2 + pcs;
      if (q == 0) aSrc0 = p; else aSrc1 = p;
    }
  }
  const char* bSrc0 = (const char*)wbT + (size_t)(      srow) * KTOT * 2 + pcs;
  const char* bSrc1 = (const char*)wbT + (size_t)(128 + srow) * KTOT * 2 + pcs;

  // ---- frag read lane offsets (swizzled koff; R3 verbatim, 0 conflicts) ----
  const int koff = (((l >> 4) ^ ((l >> 1) & 3)) << 4);
  const int raOff = (wm * 128 + lm) * 64 + koff;   // + g*1024 (g=0..7)
  const int rbOff = (wn * 64 + lm) * 64 + koff;    // + h*1024 (B region +16384)

  char* B0 = lds_;
  char* B1 = lds_ + 32768;
  char* B2 = lds_ + 65536;

// 4 gloads/thread: A rows 0-127, A rows 128-255, B oc 0-127, B oc 128-255
#define STAGE(U, BUF)                                                        \
  {                                                                          \
    const int ao_ = stage_aoff(U);                                           \
    const int bo_ = (U) * 64;                                                \
    gload16(aSrc0 + ao_, (BUF) +         wv * 1024);                         \
    gload16(aSrc1 + ao_, (BUF) +  8192 + wv * 1024);                         \
    gload16(bSrc0 + bo_, (BUF) + 16384 + wv * 1024);                         \
    gload16(bSrc1 + bo_, (BUF) + 24576 + wv * 1024);                         \
  }

  f32x4 acc[8][4];
#pragma unroll
  for (int g = 0; g < 8; ++g)
#pragma unroll
    for (int h = 0; h < 4; ++h) acc[g][h] = {0.f, 0.f, 0.f, 0.f};

  // ---- prologue: stage tiles 0,1; confirm tile 0 (leave tile 1's 4) ----
  STAGE(0, B0)
  STAGE(1, B1)
  asm volatile("s_waitcnt vmcnt(4)" ::: "memory");
  __builtin_amdgcn_s_barrier();
  __builtin_amdgcn_sched_barrier(0);

#define TILE_BODY(V, CUR, STG)                                               \
  {                                                                          \
    const int v_ = (V);                                                      \
    if (v_ + 2 < NKT) STAGE(v_ + 2, STG)                                     \
    bf16x8 af[8], bf[4];                                                     \
    _Pragma("unroll") for (int g = 0; g < 8; ++g)                            \
        af[g] = *(const bf16x8*)((CUR) + raOff + g * 1024);                  \
    _Pragma("unroll") for (int h = 0; h < 4; ++h)                            \
        bf[h] = *(const bf16x8*)((CUR) + 16384 + rbOff + h * 1024);          \
    __builtin_amdgcn_s_setprio(1);                                           \
    _Pragma("unroll") for (int g = 0; g < 8; ++g)                            \
      _Pragma("unroll") for (int h = 0; h < 4; ++h)                          \
        acc[g][h] = __builtin_amdgcn_mfma_f32_16x16x32_bf16(                 \
            bf[h], af[g], acc[g][h], 0, 0, 0);                               \
    __builtin_amdgcn_s_setprio(0);                                           \
    if (v_ < NKT - 1) {                                                      \
      if (v_ == NKT - 2) { asm volatile("s_waitcnt vmcnt(0)" ::: "memory"); }\
      else               { asm volatile("s_waitcnt vmcnt(4)" ::: "memory"); }\
      __builtin_amdgcn_s_barrier();                                          \
      __builtin_amdgcn_sched_barrier(0);                                     \
    }                                                                        \
  }

  for (int v3 = 0; v3 < NKT; v3 += 3) {
    TILE_BODY(v3 + 0, B0, B2)   // tile v reads buf v%3, stages v+2 into (v+2)%3
    TILE_BODY(v3 + 1, B1, B0)
    TILE_BODY(v3 + 2, B2, B1)
  }
#undef TILE_BODY
#undef STAGE

  // ---- epilogue: D rows = oc, cols = m (swapped operands); R3 verbatim ----
  const int mBase = mt * 256 + wm * 128 + lm;
  const int ocB   = wn * 64 + (l >> 4) * 4;
  float bv[4][4];
#pragma unroll
  for (int h = 0; h < 4; ++h)
#pragma unroll
    for (int j = 0; j < 4; ++j) bv[h][j] = bias[ocB + h * 16 + j];
#pragma unroll
  for (int g = 0; g < 8; ++g) {
    const int m  = mBase + g * 16;
    const int nb = m / 3136;
    const int hw = m - nb * 3136;
    float* op = out + (size_t)nb * CO * 3136 + hw;
#pragma unroll
    for (int h = 0; h < 4; ++h) {
      const int oc = ocB + h * 16;
#pragma unroll
      for (int j = 0; j < 4; ++j)
        op[(size_t)(oc + j) * 3136] = acc[g][h][j] + bv[h][j];
    }
  }
}

// ---------------- fallback (ws too small): naive direct conv ----------------
__global__ void conv_naive(const float* __restrict__ x, const float* __restrict__ wt,
                           const float* __restrict__ bias, float* __restrict__ out) {
  const int idx = blockIdx.x * 256 + threadIdx.x;
  if (idx >= NB * CO * 3136) return;
  const int w  = idx % HW_;
  const int h  = (idx / HW_) % HW_;
  const int oc = (idx / 3136) % CO;
  const int nb = idx / (3136 * CO);
  float s = bias[oc];
  for (int c = 0; c < CI; ++c)
    for (int kh = 0; kh < 3; ++kh) {
      const int ih = h + kh - 1;
      if (ih < 0 || ih >= HW_) continue;
      for (int kw = 0; kw < 3; ++kw) {
        const int iw = w + kw - 1;
        if (iw < 0 || iw >= HW_) continue;
        s += x[((size_t)(nb * CI + c) * HW_ + ih) * HW_ + iw] *
             wt[(((size_t)oc * CI + c) * 3 + kh) * 3 + kw];
      }
    }
  out[idx] = s;
}

extern "C" void kernel_launch(void* const* d_in, const int* in_sizes, int n_in,
                              void* d_out, int out_size, void* d_ws, size_t ws_size,
                              hipStream_t stream) {
  const float* x    = (const float*)d_in[0];
  const float* wt   = (const float*)d_in[1];
  const float* bias = (const float*)d_in[2];
  float* out        = (float*)d_out;

  if (ws_size < XP_BYTES + WT_BYTES) {
    conv_naive<<<(NB * CO * 3136 + 255) / 256, 256, 0, stream>>>(x, wt, bias, out);
    return;
  }

  short* xp  = (short*)d_ws;
  short* wbT = (short*)((char*)d_ws + XP_BYTES);

  pad_convert<<<NB * HP, 256, 0, stream>>>(x, xp, wt, wbT);
  conv_gemm<<<MTOT / 256, 512, 0, stream>>>(xp, wbT, bias, out);
}

// Round 12
// 92.894 us; speedup vs baseline: 1.5335x; 1.0303x over previous
//
#include <hip/hip_runtime.h>
#include <cstdint>
#include <cstddef>

// ---------------- problem constants ----------------
#define NB    32          // batch
#define CI    128         // in channels
#define CO    256         // out channels
#define HW_   56          // spatial
#define HP    58          // padded spatial
#define KTOT  1152        // 128*9 reduction
#define NKT   36          // K-tiles of 32
#define MTOT  (NB * HW_ * HW_)   // 100352 output pixels
#define BM    224         // M-tile (14 x 16); 448 M-tiles exactly

static constexpr size_t XP_ELEMS = (size_t)NB * HP * HP * CI;   // 13,776,896
static constexpr size_t WT_ELEMS = (size_t)CO * KTOT;           // 294,912
static constexpr size_t XP_BYTES = XP_ELEMS * 2;
static constexpr size_t WT_BYTES = WT_ELEMS * 2;

typedef __attribute__((ext_vector_type(8))) short bf16x8;
typedef __attribute__((ext_vector_type(4))) float f32x4;

__device__ __forceinline__ short f32_to_bf16(float f) {
  uint32_t u = __float_as_uint(f);
  uint32_t r = (u + 0x7FFFu + ((u >> 16) & 1u)) >> 16;
  return (short)r;
}

typedef __attribute__((address_space(3))) void       lds_void;
typedef const __attribute__((address_space(1))) void gbl_void;

__device__ __forceinline__ void gload16(const void* g, void* l) {
  // dest = wave-uniform LDS base; HW writes lane's 16B at base + lane*16
  __builtin_amdgcn_global_load_lds((gbl_void*)g, (lds_void*)l, 16, 0, 0);
}

// ---- pre-pass: x NCHW f32 -> padded NHWC bf16; wt OIHW -> [o][kh][kw][c] bf16 ----
// (verified-correct R4 version)
__global__ void pad_convert(const float* __restrict__ x, short* __restrict__ xp,
                            const float* __restrict__ wt, short* __restrict__ wbT) {
  __shared__ float lds[CI][57];
  const int blk = blockIdx.x;    // NB*HP = 1856
  const int hp  = blk % HP;
  const int nb  = blk / HP;
  const int tid = threadIdx.x;   // 256

  if (blk < 1152) {              // 1152*256 == WT_ELEMS (scalar per thread)
    int idx = blk * 256 + tid;
    int c  = idx & 127;
    int t  = idx >> 7;          // o*9 + kh*3 + kw
    int kw = t % 3;  int t2 = t / 3;
    int kh = t2 % 3; int o  = t2 / 3;
    wbT[idx] = f32_to_bf16(wt[(((size_t)o * CI + c) * 3 + kh) * 3 + kw]);
  }

  const bool interior = (hp >= 1 && hp <= HW_);
  if (interior) {
    const float* src = x + (size_t)nb * CI * HW_ * HW_ + (size_t)(hp - 1) * HW_;
    for (int t = tid; t < CI * HW_; t += 256) {
      int c = t / HW_, w = t - (t / HW_) * HW_;
      lds[c][w] = src[(size_t)c * HW_ * HW_ + w];
    }
  }
  __syncthreads();
  short* dst = xp + (size_t)(nb * HP + hp) * HP * CI;
  for (int t = tid; t < HP * CI / 4; t += 256) {
    const int wp = t >> 5;
    const int c4 = (t & 31) * 4;
    short4 s;
    if (interior && wp >= 1 && wp <= HW_) {
      s.x = f32_to_bf16(lds[c4 + 0][wp - 1]);
      s.y = f32_to_bf16(lds[c4 + 1][wp - 1]);
      s.z = f32_to_bf16(lds[c4 + 2][wp - 1]);
      s.w = f32_to_bf16(lds[c4 + 3][wp - 1]);
    } else {
      s.x = s.y = s.z = s.w = 0;
    }
    *(short4*)(dst + t * 4) = s;
  }
}

// scalar byte offset into an xp pixel row for K-tile u (tap + channel-quarter)
__device__ __forceinline__ int stage_aoff(int u) {
  const int tap = u >> 2;            // 0..8
  const int cq  = u & 3;             // channel quarter (32 ch)
  const int kh  = tap / 3, kw = tap - kh * 3;
  return ((kh * HP + kw) * CI + cq * 32) * 2;
}

// ---------------- main: implicit GEMM, 224x128 tile, BK=32, 4 waves ----------------
// R12 = R4's proven structure (counted vmcnt(6), 3 x 24KB buffers, 2 blocks/CU,
// zero-conflict swizzle) with the M-geometry changed to kill the scheduling
// tail: M = 100352 = 448 x 224 -> grid 896 over 512 block-slots = 1.75 rounds
// (eff 0.875) instead of 784/512 = 1.53 (eff 0.766). Per-wave tile 112x64
// (7 m-frags x 4 n-frags). A-stage keeps 4 gloads (rows 0..255); rows 224-255
// are garbage (sources clamped in-bounds, frag reads never touch rows > 223).
__global__ __launch_bounds__(256, 2) void conv_gemm(
    const short* __restrict__ xp, const short* __restrict__ wbT,
    const float* __restrict__ bias, float* __restrict__ out) {
  __shared__ __align__(16) char lds_[3 * 24576];

  const int tid = threadIdx.x;     // 256
  const int l   = tid & 63;
  const int wv  = tid >> 6;        // 0..3
  const int wm  = wv >> 1;         // 0..1  (m half: 112 rows)
  const int wn  = wv & 1;          // 0..1  (oc half: 64 cols)

  // grid 896 = 8 XCDs x 112; chunked bijective swizzle, nt inner (A reuse in L2)
  const int bid = blockIdx.x;
  const int lin = (bid & 7) * 112 + (bid >> 3);
  const int mt  = lin >> 1;        // 0..447
  const int nt  = lin & 1;

  // ---- staging source pointers (pre-swizzled per rule #21; R4 verbatim) ----
  // gload g covers rows 64g + 16wv + (l>>2); lane piece (l&3); src piece ^((l>>3)&3)
  const int pcs  = (((l & 3) ^ ((l >> 3) & 3)) << 4);
  const int srow = 16 * wv + (l >> 2);                 // 0..63 per gload group
  const char *aSrc0, *aSrc1, *aSrc2, *aSrc3;
  {
#pragma unroll
    for (int g = 0; g < 4; ++g) {
      int m  = mt * BM + 64 * g + srow;
      if (m >= MTOT) m = 0;            // clamp: garbage rows 224-255, never read
      int nb = m / 3136, hw = m - nb * 3136;
      int h = hw / HW_, w = hw - (hw / HW_) * HW_;
      const char* p = (const char*)xp + ((size_t)((nb * HP + h) * HP + w) * CI) * 2 + pcs;
      if (g == 0) aSrc0 = p; else if (g == 1) aSrc1 = p;
      else if (g == 2) aSrc2 = p; else aSrc3 = p;
    }
  }
  const char* bSrc0 = (const char*)wbT + (size_t)(nt * 128 +      srow) * KTOT * 2 + pcs;
  const char* bSrc1 = (const char*)wbT + (size_t)(nt * 128 + 64 + srow) * KTOT * 2 + pcs;

  // ---- frag read lane offsets (swizzled koff; R4 verbatim, 0 conflicts) ----
  const int lm   = l & 15;
  const int koff = (((l >> 4) ^ ((l >> 1) & 3)) << 4);
  const int raOff = (wm * 112 + lm) * 64 + koff;   // + g*1024, g=0..6
  const int rbOff = (wn * 64 + lm) * 64 + koff;    // + h*1024 (B region +16384)

  char* B0 = lds_;
  char* B1 = lds_ + 24576;
  char* B2 = lds_ + 49152;

#define STAGE(U, BUF)                                                        \
  {                                                                          \
    const int ao_ = stage_aoff(U);                                           \
    const int bo_ = (U) * 64;                                                \
    gload16(aSrc0 + ao_, (BUF) +         wv * 1024);                         \
    gload16(aSrc1 + ao_, (BUF) +  4096 + wv * 1024);                         \
    gload16(aSrc2 + ao_, (BUF) +  8192 + wv * 1024);                         \
    gload16(aSrc3 + ao_, (BUF) + 12288 + wv * 1024);                         \
    gload16(bSrc0 + bo_, (BUF) + 16384 + wv * 1024);                         \
    gload16(bSrc1 + bo_, (BUF) + 20480 + wv * 1024);                         \
  }

  f32x4 acc[7][4];
#pragma unroll
  for (int g = 0; g < 7; ++g)
#pragma unroll
    for (int h = 0; h < 4; ++h) acc[g][h] = {0.f, 0.f, 0.f, 0.f};

  // ---- prologue: stage tiles 0,1; confirm tile 0 ----
  STAGE(0, B0)
  STAGE(1, B1)
  asm volatile("s_waitcnt vmcnt(6)" ::: "memory");   // tile 0 landed
  __builtin_amdgcn_s_barrier();
  __builtin_amdgcn_sched_barrier(0);

#define TILE_BODY(V, CUR, STG)                                               \
  {                                                                          \
    const int v_ = (V);                                                      \
    if (v_ + 2 < NKT) STAGE(v_ + 2, STG)                                     \
    bf16x8 af[7], bf[4];                                                     \
    _Pragma("unroll") for (int g = 0; g < 7; ++g)                            \
        af[g] = *(const bf16x8*)((CUR) + raOff + g * 1024);                  \
    _Pragma("unroll") for (int h = 0; h < 4; ++h)                            \
        bf[h] = *(const bf16x8*)((CUR) + 16384 + rbOff + h * 1024);          \
    __builtin_amdgcn_s_setprio(1);                                           \
    _Pragma("unroll") for (int g = 0; g < 7; ++g)                            \
      _Pragma("unroll") for (int h = 0; h < 4; ++h)                          \
        acc[g][h] = __builtin_amdgcn_mfma_f32_16x16x32_bf16(                 \
            bf[h], af[g], acc[g][h], 0, 0, 0);                               \
    __builtin_amdgcn_s_setprio(0);                                           \
    if (v_ < NKT - 1) {                                                      \
      if (v_ == NKT - 2) { asm volatile("s_waitcnt vmcnt(0)" ::: "memory"); }\
      else               { asm volatile("s_waitcnt vmcnt(6)" ::: "memory"); }\
      __builtin_amdgcn_s_barrier();                                          \
      __builtin_amdgcn_sched_barrier(0);                                     \
    }                                                                        \
  }

  for (int v3 = 0; v3 < NKT; v3 += 3) {
    TILE_BODY(v3 + 0, B0, B2)   // tile v reads buf v%3, stages v+2 into (v+2)%3
    TILE_BODY(v3 + 1, B1, B0)
    TILE_BODY(v3 + 2, B2, B1)
  }
#undef TILE_BODY
#undef STAGE

  // ---- epilogue: D rows = oc, cols = m (swapped operands) -> coalesced stores ----
  const int mBase = mt * BM + wm * 112 + lm;
  const int ocB   = nt * 128 + wn * 64 + (l >> 4) * 4;
  float bv[4][4];
#pragma unroll
  for (int h = 0; h < 4; ++h)
#pragma unroll
    for (int j = 0; j < 4; ++j) bv[h][j] = bias[ocB + h * 16 + j];
#pragma unroll
  for (int g = 0; g < 7; ++g) {
    const int m  = mBase + g * 16;
    const int nb = m / 3136;
    const int hw = m - nb * 3136;
    float* op = out + (size_t)nb * CO * 3136 + hw;
#pragma unroll
    for (int h = 0; h < 4; ++h) {
      const int oc = ocB + h * 16;
#pragma unroll
      for (int j = 0; j < 4; ++j)
        op[(size_t)(oc + j) * 3136] = acc[g][h][j] + bv[h][j];
    }
  }
}

// ---------------- fallback (ws too small): naive direct conv ----------------
__global__ void conv_naive(const float* __restrict__ x, const float* __restrict__ wt,
                           const float* __restrict__ bias, float* __restrict__ out) {
  const int idx = blockIdx.x * 256 + threadIdx.x;
  if (idx >= NB * CO * 3136) return;
  const int w  = idx % HW_;
  const int h  = (idx / HW_) % HW_;
  const int oc = (idx / 3136) % CO;
  const int nb = idx / (3136 * CO);
  float s = bias[oc];
  for (int c = 0; c < CI; ++c)
    for (int kh = 0; kh < 3; ++kh) {
      const int ih = h + kh - 1;
      if (ih < 0 || ih >= HW_) continue;
      for (int kw = 0; kw < 3; ++kw) {
        const int iw = w + kw - 1;
        if (iw < 0 || iw >= HW_) continue;
        s += x[((size_t)(nb * CI + c) * HW_ + ih) * HW_ + iw] *
             wt[(((size_t)oc * CI + c) * 3 + kh) * 3 + kw];
      }
    }
  out[idx] = s;
}

extern "C" void kernel_launch(void* const* d_in, const int* in_sizes, int n_in,
                              void* d_out, int out_size, void* d_ws, size_t ws_size,
                              hipStream_t stream) {
  const float* x    = (const float*)d_in[0];
  const float* wt   = (const float*)d_in[1];
  const float* bias = (const float*)d_in[2];
  float* out        = (float*)d_out;

  if (ws_size < XP_BYTES + WT_BYTES) {
    conv_naive<<<(NB * CO * 3136 + 255) / 256, 256, 0, stream>>>(x, wt, bias, out);
    return;
  }

  short* xp  = (short*)d_ws;
  short* wbT = (short*)((char*)d_ws + XP_BYTES);

  pad_convert<<<NB * HP, 256, 0, stream>>>(x, xp, wt, wbT);
  conv_gemm<<<(MTOT / BM) * 2, 256, 0, stream>>>(xp, wbT, bias, out);
}